// Round 10
// baseline (884.586 us; speedup 1.0000x reference)
//
#include <hip/hip_runtime.h>
#include <hip/hip_bf16.h>

// SDEnet R10: FUSED persistent-row kernel. Each block owns 64 rows; out-panel lives in
// LDS (frag-linear, 128 KB) across ALL layers. Layer GEMM: A-frags from LDS (read-only,
// NO barriers in K-loop), B-frags (W) global->register from L2 (W is 2 MB, shared by all
// blocks). Eliminates all inter-layer HBM round-trips (~1.1 GB). 2 barriers/layer.
// zw pre-pass unchanged (only reader of noise).

typedef unsigned short u16;
typedef __attribute__((ext_vector_type(8))) short short8;
typedef __attribute__((ext_vector_type(8))) u16 u16x8;
typedef __attribute__((ext_vector_type(4))) float f32x4;
typedef __attribute__((ext_vector_type(16))) float f32x16;

#define BROWS 32768
#define DDIM 1024
#define NBLK 5
#define H_STEP 0.1f
#define SQRT_H 0.31622776601683794f

__device__ __forceinline__ float bf2f(u16 u) {
    return __uint_as_float(((unsigned)u) << 16);
}
__device__ __forceinline__ u16 f2bf(float f) {
    unsigned u = __float_as_uint(f);
    unsigned r = 0x7fffu + ((u >> 16) & 1u);
    return (u16)((u + r) >> 16);
}
__device__ __forceinline__ float fast_tanh(float s) {
    float e = __expf(2.0f * s);
    return 1.0f - 2.0f * __builtin_amdgcn_rcpf(e + 1.0f);
}

// async global -> LDS, 16B per lane, wave-uniform LDS base + lane*16 (per-lane global src)
#define GLOAD_LDS16(g, l)                                                        \
    __builtin_amdgcn_global_load_lds(                                            \
        (const __attribute__((address_space(1))) unsigned int*)(const void*)(g), \
        (__attribute__((address_space(3))) unsigned int*)(void*)(l), 16, 0, 0)

// ---------------- pad/convert fp32 -> bf16 (optionally zero-padded cols) ----------------
__global__ __launch_bounds__(256) void pad_cvt(const float* __restrict__ src,
                                               u16* __restrict__ dst,
                                               int R, int C, int Cp) {
    int idx = blockIdx.x * 256 + threadIdx.x;
    if (idx >= R * Cp) return;
    int r = idx / Cp;
    int c = idx - r * Cp;
    float v = (c < C) ? src[(size_t)r * C + c] : 0.0f;
    dst[idx] = f2bf(v);
}

// ---------------- zw[i][b] = sum_d noise[i][b][d] * bw[i][d]  (one wave per row) --------
__global__ __launch_bounds__(256) void zw_kernel(const float* __restrict__ noise,
                                                 const float* __restrict__ bw,
                                                 float* __restrict__ zw) {
    int gw = (blockIdx.x * 256 + threadIdx.x) >> 6;
    int lane = threadIdx.x & 63;
    if (gw >= NBLK * BROWS) return;
    int i = gw >> 15;
    const float* zr = noise + (size_t)gw * DDIM;
    const float* wr = bw + i * DDIM;
    float s = 0.0f;
#pragma unroll
    for (int it = 0; it < 4; ++it) {
        int k = it * 256 + lane * 4;
        f32x4 z = *(const f32x4*)(zr + k);
        f32x4 w = *(const f32x4*)(wr + k);
        s += z.x * w.x + z.y * w.y + z.z * w.z + z.w * w.w;
    }
#pragma unroll
    for (int off = 32; off > 0; off >>= 1) s += __shfl_down(s, off, 64);
    if (lane == 0) zw[gw] = s;
}

// ---------------- fused SDE net: 64 rows/block, panel resident in LDS -------------------
// Panel layout (frag-linear, bf16): frag(M=row>>5, kf=col>>4) at (M*64+kf)*1024 bytes;
// within frag: lane L = (row&31) + 32*((col>>3)&1) holds bytes L*16 + (col&7)*2.
// MFMA 32x32x16: A-frag lane = row&31 | k-half<<5; B-frag lane = col&31 | k-half<<5.
__global__ __launch_bounds__(512, 2) void fused_k(const u16* __restrict__ xb,
                                                  const u16* __restrict__ W0b,
                                                  const float* __restrict__ b0,
                                                  const u16* __restrict__ Wsb,
                                                  const float* __restrict__ bs,
                                                  const float* __restrict__ bwv,
                                                  const float* __restrict__ zwv,
                                                  const float* __restrict__ wlast,
                                                  const float* __restrict__ blast,
                                                  float* __restrict__ y) {
    __shared__ __align__(16) u16 smem[65536];  // 128 KiB panel
    char* lds = (char*)smem;

    const int tid = threadIdx.x;
    const int lane = tid & 63;
    const int wid = tid >> 6;      // 8 waves; wave owns cols [128*wid, 128*wid+128)
    const int lr = lane & 31;
    const int lh = lane >> 5;
    const int r0 = blockIdx.x * 64;
    const int colb = wid * 128 + lr;   // per-lane col for n-subtile 0

    // ---- stage xb panel frags (K=128 -> kf 0..7), 2 frags per wave ----
#pragma unroll
    for (int j = 0; j < 2; ++j) {
        int f = wid * 2 + j;           // 0..15
        int M = f >> 3, ks = f & 7;
        const u16* src = xb + (size_t)(r0 + M * 32 + lr) * 128 + ks * 16 + lh * 8;
        char* dst = lds + (M * 64 + ks) * 1024;
        GLOAD_LDS16(src, dst);
    }
    asm volatile("s_waitcnt vmcnt(0)" ::: "memory");
    __builtin_amdgcn_s_barrier();
    asm volatile("" ::: "memory");

    const int aM0 = lane * 16;          // A-frag read base (M=0); M=1 at +65536
    f32x16 acc[2][4];

    // ================= prologue: out0 = tanh(xb @ W0^T + b0) =================
#pragma unroll
    for (int m = 0; m < 2; ++m)
#pragma unroll
        for (int n = 0; n < 4; ++n)
#pragma unroll
            for (int e = 0; e < 16; ++e) acc[m][n][e] = 0.f;

#pragma unroll
    for (int j = 0; j < 4; ++j) {
#pragma unroll
        for (int s = 0; s < 2; ++s) {
            const int kf = 2 * j + s;
            short8 a0 = *(const short8*)(lds + aM0 + kf * 1024);
            short8 a1 = *(const short8*)(lds + aM0 + 65536 + kf * 1024);
#pragma unroll
            for (int n = 0; n < 4; ++n) {
                const u16* bp = W0b + (size_t)(colb + 32 * n) * 128 + lh * 8 + kf * 16;
                short8 bf = *(const short8*)bp;
                acc[0][n] = __builtin_amdgcn_mfma_f32_32x32x16_bf16(a0, bf, acc[0][n], 0, 0, 0);
                acc[1][n] = __builtin_amdgcn_mfma_f32_32x32x16_bf16(a1, bf, acc[1][n], 0, 0, 0);
            }
        }
    }
    asm volatile("" ::: "memory");
    __builtin_amdgcn_s_barrier();      // all reads of kf0..7 done before overwrite
    asm volatile("" ::: "memory");
    {
        float b0c[4];
#pragma unroll
        for (int n = 0; n < 4; ++n) b0c[n] = b0[colb + 32 * n];
#pragma unroll
        for (int m = 0; m < 2; ++m)
#pragma unroll
            for (int n = 0; n < 4; ++n) {
                const int c = colb + 32 * n;
                const int abase = (m * 64 + (c >> 4)) * 1024 + (((c >> 3) & 1) << 9) + (c & 7) * 2;
#pragma unroll
                for (int reg = 0; reg < 16; ++reg) {
                    int r5 = (reg & 3) + ((reg >> 2) << 3) + (lh << 2);  // row&31
                    float t = fast_tanh(acc[m][n][reg] + b0c[n]);
                    *(u16*)(lds + abase + r5 * 16) = f2bf(t);
                }
            }
    }
    asm volatile("" ::: "memory");
    __builtin_amdgcn_s_barrier();
    asm volatile("" ::: "memory");

    // ================= 5 residual layers =================
    for (int i = 0; i < NBLK; ++i) {
        const u16* Wb = Wsb + (size_t)i * DDIM * DDIM;
        float zwl = zwv[(size_t)i * BROWS + r0 + lane];   // zw for local row = lane
        float bsc[4], bwc[4];
#pragma unroll
        for (int n = 0; n < 4; ++n) {
            bsc[n] = bs[i * DDIM + colb + 32 * n];
            bwc[n] = bwv[i * DDIM + colb + 32 * n];
        }
        const u16* bp0 = Wb + (size_t)(colb + 0 * 32) * DDIM + lh * 8;
        const u16* bp1 = Wb + (size_t)(colb + 1 * 32) * DDIM + lh * 8;
        const u16* bp2 = Wb + (size_t)(colb + 2 * 32) * DDIM + lh * 8;
        const u16* bp3 = Wb + (size_t)(colb + 3 * 32) * DDIM + lh * 8;

#pragma unroll
        for (int m = 0; m < 2; ++m)
#pragma unroll
            for (int n = 0; n < 4; ++n)
#pragma unroll
                for (int e = 0; e < 16; ++e) acc[m][n][e] = 0.f;

        // ---- K-loop: NO barriers. A from resident LDS, B (W) global from L2. ----
#pragma unroll
        for (int kf = 0; kf < 64; ++kf) {
            short8 a0 = *(const short8*)(lds + aM0 + kf * 1024);
            short8 a1 = *(const short8*)(lds + aM0 + 65536 + kf * 1024);
            short8 bf0 = *(const short8*)(bp0 + kf * 16);
            short8 bf1 = *(const short8*)(bp1 + kf * 16);
            short8 bf2 = *(const short8*)(bp2 + kf * 16);
            short8 bf3 = *(const short8*)(bp3 + kf * 16);
            acc[0][0] = __builtin_amdgcn_mfma_f32_32x32x16_bf16(a0, bf0, acc[0][0], 0, 0, 0);
            acc[1][0] = __builtin_amdgcn_mfma_f32_32x32x16_bf16(a1, bf0, acc[1][0], 0, 0, 0);
            acc[0][1] = __builtin_amdgcn_mfma_f32_32x32x16_bf16(a0, bf1, acc[0][1], 0, 0, 0);
            acc[1][1] = __builtin_amdgcn_mfma_f32_32x32x16_bf16(a1, bf1, acc[1][1], 0, 0, 0);
            acc[0][2] = __builtin_amdgcn_mfma_f32_32x32x16_bf16(a0, bf2, acc[0][2], 0, 0, 0);
            acc[1][2] = __builtin_amdgcn_mfma_f32_32x32x16_bf16(a1, bf2, acc[1][2], 0, 0, 0);
            acc[0][3] = __builtin_amdgcn_mfma_f32_32x32x16_bf16(a0, bf3, acc[0][3], 0, 0, 0);
            acc[1][3] = __builtin_amdgcn_mfma_f32_32x32x16_bf16(a1, bf3, acc[1][3], 0, 0, 0);
        }
        asm volatile("" ::: "memory");
        __builtin_amdgcn_s_barrier();   // all waves done reading panel
        asm volatile("" ::: "memory");

        // ---- epilogue: out += H*tanh(acc+bs) + sqrtH*zw[row]*bw[col], in-place ----
#pragma unroll
        for (int m = 0; m < 2; ++m)
#pragma unroll
            for (int n = 0; n < 4; ++n) {
                const int c = colb + 32 * n;
                const int abase = (m * 64 + (c >> 4)) * 1024 + (((c >> 3) & 1) << 9) + (c & 7) * 2;
#pragma unroll
                for (int reg = 0; reg < 16; ++reg) {
                    int r5 = (reg & 3) + ((reg >> 2) << 3) + (lh << 2);
                    int row = m * 32 + r5;
                    float old = bf2f(*(const u16*)(lds + abase + r5 * 16));
                    float zwr = __shfl(zwl, row, 64);
                    float v = old + H_STEP * fast_tanh(acc[m][n][reg] + bsc[n])
                              + SQRT_H * zwr * bwc[n];
                    *(u16*)(lds + abase + r5 * 16) = f2bf(v);
                }
            }
        asm volatile("" ::: "memory");
        __builtin_amdgcn_s_barrier();   // writes visible before next layer's reads
        asm volatile("" ::: "memory");
    }

    // ================= final: y = out @ wlast^T + blast =================
    float wlf[16];
#pragma unroll
    for (int e = 0; e < 4; ++e) {
        f32x4 w = *(const f32x4*)(wlast + lane * 16 + e * 4);
        wlf[e * 4 + 0] = w.x; wlf[e * 4 + 1] = w.y; wlf[e * 4 + 2] = w.z; wlf[e * 4 + 3] = w.w;
    }
    const float bl = blast[0];
#pragma unroll
    for (int rr = 0; rr < 8; ++rr) {
        const int row = wid * 8 + rr;
        const int base = ((row >> 5) * 64 + lane) * 1024 + (row & 31) * 16;
        u16x8 c0 = *(const u16x8*)(lds + base);        // cols 16*lane + 0..7
        u16x8 c1 = *(const u16x8*)(lds + base + 512);  // cols 16*lane + 8..15
        float s = 0.f;
#pragma unroll
        for (int e = 0; e < 8; ++e) {
            s += bf2f(c0[e]) * wlf[e] + bf2f(c1[e]) * wlf[8 + e];
        }
#pragma unroll
        for (int off = 32; off > 0; off >>= 1) s += __shfl_down(s, off, 64);
        if (lane == 0) y[r0 + row] = s + bl;
    }
}

extern "C" void kernel_launch(void* const* d_in, const int* in_sizes, int n_in,
                              void* d_out, int out_size, void* d_ws, size_t ws_size,
                              hipStream_t stream) {
    const float* x     = (const float*)d_in[0];  // [32768,100]
    const float* W0    = (const float*)d_in[1];  // [1024,100]
    const float* b0    = (const float*)d_in[2];  // [1024]
    const float* Ws    = (const float*)d_in[3];  // [5,1024,1024]
    const float* bs    = (const float*)d_in[4];  // [5,1024]
    const float* bw    = (const float*)d_in[5];  // [5,1024]
    const float* Wlast = (const float*)d_in[6];  // [1,1024]
    const float* blast = (const float*)d_in[7];  // [1]
    const float* noise = (const float*)d_in[8];  // [5,32768,1024]
    float* y = (float*)d_out;                    // [32768]
    (void)in_sizes; (void)n_in; (void)out_size; (void)ws_size;

    char* ws = (char*)d_ws;
    size_t off = 0;
    auto alloc = [&](size_t bytes) {
        char* p = ws + off;
        off += (bytes + 255) & ~(size_t)255;
        return p;
    };
    u16* xb    = (u16*)alloc((size_t)BROWS * 128 * 2);        // 8 MB
    u16* W0b   = (u16*)alloc((size_t)DDIM * 128 * 2);         // 256 KB
    u16* Wsb   = (u16*)alloc((size_t)NBLK * DDIM * DDIM * 2); // 10 MB
    float* zw  = (float*)alloc((size_t)NBLK * BROWS * 4);     // 640 KB

    // convert inputs to bf16 (x, W0 padded K 100->128)
    pad_cvt<<<(BROWS * 128 + 255) / 256, 256, 0, stream>>>(x, xb, BROWS, 100, 128);
    pad_cvt<<<(DDIM * 128 + 255) / 256, 256, 0, stream>>>(W0, W0b, DDIM, 100, 128);
    pad_cvt<<<(NBLK * DDIM * DDIM + 255) / 256, 256, 0, stream>>>(Ws, Wsb, NBLK * DDIM, DDIM, DDIM);

    // zw[i][b] = noise_i[b] . bw_i   (the ONLY read of noise)
    zw_kernel<<<(NBLK * BROWS) / 4, 256, 0, stream>>>(noise, bw, zw);

    // fused: prologue GEMM + 5 residual layers + final GEMV, panel resident per block
    fused_k<<<BROWS / 64, 512, 0, stream>>>(xb, W0b, b0, Wsb, bs, bw, zw, Wlast, blast, y);
}